// Round 7
// baseline (261.572 us; speedup 1.0000x reference)
//
#include <hip/hip_runtime.h>
#include <math.h>

#define T 2048
#define DM 640
#define NH 14
#define NKV 2
#define HPK 7
#define HD 64
#define QDIM 896
#define QKV_DIM 1152

// 64^-0.25 * sqrt(log2(e)): folds base-2 softmax into Q/K scaling
constexpr float QK_SCALE2 = 0.35355339059327373f * 1.2011224087864498f;
constexpr float EPSF = 1e-5f;

typedef __attribute__((ext_vector_type(8))) short short8;   // 8 bf16 = 4 VGPR
typedef __attribute__((ext_vector_type(4))) float float4v;  // MFMA acc
typedef unsigned short ush;

static __device__ __forceinline__ ush f2bf(float f) {
    union { float f; unsigned u; } v; v.f = f;
    unsigned r = v.u + 0x7fffu + ((v.u >> 16) & 1u);
    return (ush)(r >> 16);
}
static __device__ __forceinline__ float bf2f(ush s) {
    union { unsigned u; float f; } v; v.u = ((unsigned)s) << 16;
    return v.f;
}

// ---------------------------------------------------------------- RMSNorm rstd (fused)
__global__ __launch_bounds__(256) void rstd_kernel(
    const float* __restrict__ x, float* __restrict__ rstd)
{
    const int t0 = blockIdx.x * 64;
    const int tl = threadIdx.x & 63, cg = threadIdx.x >> 6;
    __shared__ float red[4][64];
    float ss = 0.f;
    for (int c = cg; c < DM; c += 4) {
        const float v = x[(size_t)c * T + t0 + tl];
        ss = fmaf(v, v, ss);
    }
    red[cg][tl] = ss;
    __syncthreads();
    if (threadIdx.x < 64) {
        const float s = red[0][tl] + red[1][tl] + red[2][tl] + red[3][tl];
        rstd[t0 + tl] = rsqrtf(s * (1.0f / DM) + EPSF);
    }
}

// ------------------------------------------------- both weight casts in one launch
__global__ __launch_bounds__(256) void cast2_kernel(
    const float* __restrict__ a, ush* __restrict__ ah, ush* __restrict__ al, int na4,
    const float* __restrict__ b, ush* __restrict__ bh, ush* __restrict__ bl)
{
    const int i = blockIdx.x * 256 + threadIdx.x;
    const float* src; ush *dh, *dl; int j;
    if (i < na4) { src = a; dh = ah; dl = al; j = i; }
    else         { src = b; dh = bh; dl = bl; j = i - na4; }
    const float4 v = ((const float4*)src)[j];
    ushort4 h, l;
    h.x = f2bf(v.x); l.x = f2bf(v.x - bf2f(h.x));
    h.y = f2bf(v.y); l.y = f2bf(v.y - bf2f(h.y));
    h.z = f2bf(v.z); l.z = f2bf(v.z - bf2f(h.z));
    h.w = f2bf(v.w); l.w = f2bf(v.w - bf2f(h.w));
    ((ushort4*)dh)[j] = h;
    ((ushort4*)dl)[j] = l;
}

// ------------------------------------------------- normed x, transposed to [t][c]
__global__ __launch_bounds__(256) void xnorm_kernel(
    const float* __restrict__ x, const float* __restrict__ norm_w,
    const float* __restrict__ rstd,
    ush* __restrict__ XnH, ush* __restrict__ XnL)
{
    const int tid = threadIdx.x;
    const int t0 = blockIdx.x * 64;
    const int c0 = blockIdx.y * 64;
    __shared__ float xs[64][65];

    #pragma unroll
    for (int it = 0; it < 4; ++it) {
        const int r = (tid >> 4) + it * 16;
        const int cl = (tid & 15) * 4;
        const float4 v = *(const float4*)&x[(size_t)(c0 + r) * T + t0 + cl];
        xs[r][cl + 0] = v.x; xs[r][cl + 1] = v.y;
        xs[r][cl + 2] = v.z; xs[r][cl + 3] = v.w;
    }
    __syncthreads();
    #pragma unroll
    for (int it = 0; it < 4; ++it) {
        const int tr = (tid >> 4) + it * 16;
        const int cl = (tid & 15) * 4;
        const float rs = rstd[t0 + tr];
        ushort4 h, l;
        const float v0 = xs[cl + 0][tr] * norm_w[c0 + cl + 0] * rs;
        const float v1 = xs[cl + 1][tr] * norm_w[c0 + cl + 1] * rs;
        const float v2 = xs[cl + 2][tr] * norm_w[c0 + cl + 2] * rs;
        const float v3 = xs[cl + 3][tr] * norm_w[c0 + cl + 3] * rs;
        h.x = f2bf(v0); l.x = f2bf(v0 - bf2f(h.x));
        h.y = f2bf(v1); l.y = f2bf(v1 - bf2f(h.y));
        h.z = f2bf(v2); l.z = f2bf(v2 - bf2f(h.z));
        h.w = f2bf(v3); l.w = f2bf(v3 - bf2f(h.w));
        *(ushort4*)&XnH[(size_t)(t0 + tr) * DM + c0 + cl] = h;
        *(ushort4*)&XnL[(size_t)(t0 + tr) * DM + c0 + cl] = l;
    }
}

// ------------------------------------------------- QKV MFMA GEMM (+bias+RoPE), true 2-phase
#define QSX_H 0
#define QSX_L 8192
#define QSW_H 16384
#define QSW_L 24576

__global__ __launch_bounds__(256) void qkv_mfma_kernel(
    const ush* __restrict__ XnH, const ush* __restrict__ XnL,
    const ush* __restrict__ WH, const ush* __restrict__ WL,
    const float* __restrict__ qkv_b, const float* __restrict__ rope_cos,
    const float* __restrict__ rope_sin,
    ush* __restrict__ Qh, ush* __restrict__ Ql,
    ush* __restrict__ Kh, ush* __restrict__ Kl,
    ush* __restrict__ Vth, ush* __restrict__ Vtl)
{
    const int t0 = blockIdx.x * 64;
    const int o0 = blockIdx.y * 64;
    const int tid = threadIdx.x;
    const int wave = tid >> 6, lane = tid & 63;
    const int lg = lane >> 4, lq = lane & 15;
    const int wr = wave >> 1, wc = wave & 1;

    __shared__ __align__(16) unsigned char sm[65536];

    const int srow0 = tid >> 3, srow1 = srow0 + 32, scc = tid & 7;
    const int dst0 = srow0 * 128 + ((scc * 16) ^ ((srow0 & 7) << 4));
    const int dst1 = srow1 * 128 + ((scc * 16) ^ ((srow1 & 7) << 4));

    uint4 xh0, xl0, wh0, wl0, xh1, xl1, wh1, wl1;

#define QLOAD(c_) do { \
    xh0 = *(const uint4*)&XnH[(size_t)(t0 + srow0) * DM + (c_) + scc * 8]; \
    xl0 = *(const uint4*)&XnL[(size_t)(t0 + srow0) * DM + (c_) + scc * 8]; \
    wh0 = *(const uint4*)&WH [(size_t)(o0 + srow0) * DM + (c_) + scc * 8]; \
    wl0 = *(const uint4*)&WL [(size_t)(o0 + srow0) * DM + (c_) + scc * 8]; \
    xh1 = *(const uint4*)&XnH[(size_t)(t0 + srow1) * DM + (c_) + scc * 8]; \
    xl1 = *(const uint4*)&XnL[(size_t)(t0 + srow1) * DM + (c_) + scc * 8]; \
    wh1 = *(const uint4*)&WH [(size_t)(o0 + srow1) * DM + (c_) + scc * 8]; \
    wl1 = *(const uint4*)&WL [(size_t)(o0 + srow1) * DM + (c_) + scc * 8]; \
} while (0)

#define QSTORE(b_) do { \
    *(uint4*)((b_) + QSX_H + dst0) = xh0; \
    *(uint4*)((b_) + QSX_L + dst0) = xl0; \
    *(uint4*)((b_) + QSW_H + dst0) = wh0; \
    *(uint4*)((b_) + QSW_L + dst0) = wl0; \
    *(uint4*)((b_) + QSX_H + dst1) = xh1; \
    *(uint4*)((b_) + QSX_L + dst1) = xl1; \
    *(uint4*)((b_) + QSW_H + dst1) = wh1; \
    *(uint4*)((b_) + QSW_L + dst1) = wl1; \
} while (0)

    float4v acc[2][2];
    acc[0][0] = (float4v)0.f; acc[0][1] = (float4v)0.f;
    acc[1][0] = (float4v)0.f; acc[1][1] = (float4v)0.f;

    QLOAD(0);
    QSTORE(sm);
    int cur = 0;
    for (int s = 0; s < 10; ++s) {
        __syncthreads();                       // buf[cur] ready
        if (s < 9) QLOAD((s + 1) * 64);        // issue AFTER barrier -> overlaps compute
        const unsigned char* smb = sm + cur * 32768;
        #pragma unroll
        for (int kk = 0; kk < 2; ++kk) {
            short8 ah[2], al[2], bh[2], bl[2];
            #pragma unroll
            for (int nt = 0; nt < 2; ++nt) {
                const int row = wc * 32 + nt * 16 + lq;
                const int col = (kk * 64 + lg * 16) ^ ((row & 7) << 4);
                bh[nt] = *(const short8*)(smb + QSX_H + row * 128 + col);
                bl[nt] = *(const short8*)(smb + QSX_L + row * 128 + col);
            }
            #pragma unroll
            for (int mt = 0; mt < 2; ++mt) {
                const int row = wr * 32 + mt * 16 + lq;
                const int col = (kk * 64 + lg * 16) ^ ((row & 7) << 4);
                ah[mt] = *(const short8*)(smb + QSW_H + row * 128 + col);
                al[mt] = *(const short8*)(smb + QSW_L + row * 128 + col);
            }
            #pragma unroll
            for (int mt = 0; mt < 2; ++mt) {
                #pragma unroll
                for (int nt = 0; nt < 2; ++nt) {
                    acc[mt][nt] = __builtin_amdgcn_mfma_f32_16x16x32_bf16(ah[mt], bh[nt], acc[mt][nt], 0, 0, 0);
                    acc[mt][nt] = __builtin_amdgcn_mfma_f32_16x16x32_bf16(ah[mt], bl[nt], acc[mt][nt], 0, 0, 0);
                    acc[mt][nt] = __builtin_amdgcn_mfma_f32_16x16x32_bf16(al[mt], bh[nt], acc[mt][nt], 0, 0, 0);
                }
            }
        }
        if (s < 9) { QSTORE(sm + ((cur ^ 1) * 32768)); cur ^= 1; } // vmcnt wait lands here
    }
#undef QLOAD
#undef QSTORE

    const int by = blockIdx.y;
    #pragma unroll
    for (int mt = 0; mt < 2; ++mt) {
        const int d0 = wr * 32 + mt * 16 + lg * 4;
        #pragma unroll
        for (int nt = 0; nt < 2; ++nt) {
            const int t = t0 + wc * 32 + nt * 16 + lq;
            if (by < 16) { // Q or K: bias + rope + scale (incl sqrt(log2e))
                const float e0 = acc[mt][nt][0] + qkv_b[o0 + d0 + 0];
                const float d1 = acc[mt][nt][1] + qkv_b[o0 + d0 + 1];
                const float e2 = acc[mt][nt][2] + qkv_b[o0 + d0 + 2];
                const float d3 = acc[mt][nt][3] + qkv_b[o0 + d0 + 3];
                const float c0v = rope_cos[t * 32 + (d0 >> 1)];
                const float s0v = rope_sin[t * 32 + (d0 >> 1)];
                const float c1v = rope_cos[t * 32 + (d0 >> 1) + 1];
                const float s1v = rope_sin[t * 32 + (d0 >> 1) + 1];
                const float r0 = (e0 * c0v - d1 * s0v) * QK_SCALE2;
                const float r1 = (d1 * c0v + e0 * s0v) * QK_SCALE2;
                const float r2 = (e2 * c1v - d3 * s1v) * QK_SCALE2;
                const float r3 = (d3 * c1v + e2 * s1v) * QK_SCALE2;
                ushort4 h, l;
                h.x = f2bf(r0); l.x = f2bf(r0 - bf2f(h.x));
                h.y = f2bf(r1); l.y = f2bf(r1 - bf2f(h.y));
                h.z = f2bf(r2); l.z = f2bf(r2 - bf2f(h.z));
                h.w = f2bf(r3); l.w = f2bf(r3 - bf2f(h.w));
                if (by < 14) {
                    *(ushort4*)&Qh[((size_t)(by * T + t)) * HD + d0] = h;
                    *(ushort4*)&Ql[((size_t)(by * T + t)) * HD + d0] = l;
                } else {
                    const int h2 = by - 14;
                    *(ushort4*)&Kh[((size_t)(h2 * T + t)) * HD + d0] = h;
                    *(ushort4*)&Kl[((size_t)(h2 * T + t)) * HD + d0] = l;
                }
            } else { // V: bias only, store d-major
                const int h2 = by - 16;
                #pragma unroll
                for (int j = 0; j < 4; ++j) {
                    const float val = acc[mt][nt][j] + qkv_b[o0 + d0 + j];
                    const ush hh = f2bf(val);
                    Vth[((size_t)(h2 * HD + d0 + j)) * T + t] = hh;
                    Vtl[((size_t)(h2 * HD + d0 + j)) * T + t] = f2bf(val - bf2f(hh));
                }
            }
        }
    }
}

// --------------------------------------------- attention: MFMA flash, strided split-K=2
// block (qt, h, kc): processes k-tiles kt = kc, kc+2, ... <= qt. True 2-phase pipeline.
__global__ __launch_bounds__(256) void attn_mfma_kernel(
    const ush* __restrict__ Qh, const ush* __restrict__ Ql,
    const ush* __restrict__ Kh, const ush* __restrict__ Kl,
    const ush* __restrict__ Vth, const ush* __restrict__ Vtl,
    const float* __restrict__ sinks,
    float* __restrict__ Opart, float* __restrict__ Mpart, float* __restrict__ Lpart)
{
    const int qt = 31 - (int)blockIdx.x;   // longest blocks dispatch first
    const int h  = blockIdx.y;
    const int kc = blockIdx.z;
    const int kvh = h / HPK;
    const int tid = threadIdx.x;
    const int wave = tid >> 6, lane = tid & 63;
    const int lg = lane >> 4, lq = lane & 15;
    const int qbase = qt * 64 + wave * 16;
    const int myq = qbase + lq;

    __shared__ __align__(16) unsigned char sm[2 * 32768 + 4 * 2304];
    unsigned int* Pl = (unsigned int*)(sm + 65536) + wave * (16 * 36);

    short8 qf[2][2];
    #pragma unroll
    for (int kk = 0; kk < 2; ++kk) {
        const size_t qoff = ((size_t)(h * T + myq)) * HD + kk * 32 + lg * 8;
        qf[kk][0] = *(const short8*)&Qh[qoff];
        qf[kk][1] = *(const short8*)&Ql[qoff];
    }

    float4v oacc[4];
    #pragma unroll
    for (int dt = 0; dt < 4; ++dt) oacc[dt] = (float4v)0.f;

    float m2, l;
    if (kc == 0) { m2 = sinks[h]; l = 1.0f; }  // sink logit in base-2 units
    else         { m2 = -3e38f;   l = 0.0f; }

    const ush* Khp = Kh + (size_t)kvh * T * HD;
    const ush* Klp = Kl + (size_t)kvh * T * HD;
    const ush* Vhp = Vth + (size_t)kvh * HD * T;
    const ush* Vlp = Vtl + (size_t)kvh * HD * T;

    const int srow0 = tid >> 3, srow1 = srow0 + 32, scc = tid & 7;
    const int dst0 = srow0 * 128 + ((scc * 16) ^ ((srow0 & 7) << 4));
    const int dst1 = srow1 * 128 + ((scc * 16) ^ ((srow1 & 7) << 4));

    uint4 rk0h, rk0l, rv0h, rv0l, rk1h, rk1l, rv1h, rv1l;

#define ALOAD(kb_) do { \
    rk0h = *(const uint4*)(Khp + (size_t)((kb_) + srow0) * HD + scc * 8); \
    rk0l = *(const uint4*)(Klp + (size_t)((kb_) + srow0) * HD + scc * 8); \
    rv0h = *(const uint4*)(Vhp + (size_t)srow0 * T + (kb_) + scc * 8); \
    rv0l = *(const uint4*)(Vlp + (size_t)srow0 * T + (kb_) + scc * 8); \
    rk1h = *(const uint4*)(Khp + (size_t)((kb_) + srow1) * HD + scc * 8); \
    rk1l = *(const uint4*)(Klp + (size_t)((kb_) + srow1) * HD + scc * 8); \
    rv1h = *(const uint4*)(Vhp + (size_t)srow1 * T + (kb_) + scc * 8); \
    rv1l = *(const uint4*)(Vlp + (size_t)srow1 * T + (kb_) + scc * 8); \
} while (0)

#define ASTORE(b_) do { \
    *(uint4*)((b_) + 0     + dst0) = rk0h; \
    *(uint4*)((b_) + 8192  + dst0) = rk0l; \
    *(uint4*)((b_) + 16384 + dst0) = rv0h; \
    *(uint4*)((b_) + 24576 + dst0) = rv0l; \
    *(uint4*)((b_) + 0     + dst1) = rk1h; \
    *(uint4*)((b_) + 8192  + dst1) = rk1l; \
    *(uint4*)((b_) + 16384 + dst1) = rv1h; \
    *(uint4*)((b_) + 24576 + dst1) = rv1l; \
} while (0)

    const int nt_cnt = (qt >= kc) ? ((qt - kc) >> 1) + 1 : 0;
    if (nt_cnt > 0) { ALOAD(kc * 64); ASTORE(sm); }
    int cur = 0;

    for (int i = 0; i < nt_cnt; ++i) {
        const int kt = kc + 2 * i;
        const int kb = kt * 64;
        __syncthreads();                          // buf[cur] ready
        if (i + 1 < nt_cnt) ALOAD(kb + 128);      // issue AFTER barrier -> overlaps compute
        unsigned char* smb = sm + cur * 32768;

        // ---- S^T = K . Q^T (3-term hi/lo), scores already in base-2 units
        float4v st[4];
        #pragma unroll
        for (int t = 0; t < 4; ++t) st[t] = (float4v)0.f;
        #pragma unroll
        for (int t = 0; t < 4; ++t) {
            const int row = t * 16 + lq;
            const int rb = row * 128;
            const int sw = (row & 7) << 4;
            #pragma unroll
            for (int kk = 0; kk < 2; ++kk) {
                const int col = (kk * 64 + lg * 16) ^ sw;
                const short8 ah = *(const short8*)(smb + rb + col);
                const short8 al = *(const short8*)(smb + 8192 + rb + col);
                st[t] = __builtin_amdgcn_mfma_f32_16x16x32_bf16(ah, qf[kk][0], st[t], 0, 0, 0);
                st[t] = __builtin_amdgcn_mfma_f32_16x16x32_bf16(ah, qf[kk][1], st[t], 0, 0, 0);
                st[t] = __builtin_amdgcn_mfma_f32_16x16x32_bf16(al, qf[kk][0], st[t], 0, 0, 0);
            }
        }

        // ---- causal mask + online softmax (base-2)
        float pmax = -3e38f;
        #pragma unroll
        for (int t = 0; t < 4; ++t) {
            #pragma unroll
            for (int j = 0; j < 4; ++j) {
                const int key = kb + 16 * t + 4 * lg + j;
                const float s = (key > myq) ? -3e38f : st[t][j];
                st[t][j] = s;
                pmax = fmaxf(pmax, s);
            }
        }
        pmax = fmaxf(pmax, __shfl_xor(pmax, 16));
        pmax = fmaxf(pmax, __shfl_xor(pmax, 32));
        if (__any(pmax > m2)) {
            const float mnew = fmaxf(m2, pmax);
            const float corr = exp2f(m2 - mnew);
            l *= corr;
            #pragma unroll
            for (int dt = 0; dt < 4; ++dt) oacc[dt] *= corr;
            m2 = mnew;
        }
        float psum = 0.f;
        #pragma unroll
        for (int t = 0; t < 4; ++t) {
            #pragma unroll
            for (int j = 0; j < 4; ++j) {
                const float p = exp2f(st[t][j] - m2);
                st[t][j] = p;
                psum += p;
            }
        }
        psum += __shfl_xor(psum, 16);
        psum += __shfl_xor(psum, 32);
        l += psum;

        // ---- P^T fragments via per-wave LDS (in-order DS, no barrier needed)
        #pragma unroll
        for (int t = 0; t < 4; ++t) {
            #pragma unroll
            for (int j2 = 0; j2 < 2; ++j2) {
                const unsigned int u = (unsigned int)f2bf(st[t][2 * j2]) |
                                       ((unsigned int)f2bf(st[t][2 * j2 + 1]) << 16);
                Pl[lq * 36 + t * 8 + lg * 2 + j2] = u;
            }
        }

        // ---- O^T += (V_hi + V_lo) . P^T  (2-term)
        #pragma unroll
        for (int c = 0; c < 2; ++c) {
            const short8 pf = *(const short8*)&Pl[lq * 36 + c * 16 + lg * 4];
            #pragma unroll
            for (int dt = 0; dt < 4; ++dt) {
                const int row = dt * 16 + lq;
                const int rb = row * 128;
                const int col = (c * 64 + lg * 16) ^ ((row & 7) << 4);
                const short8 vh = *(const short8*)(smb + 16384 + rb + col);
                const short8 vl = *(const short8*)(smb + 24576 + rb + col);
                oacc[dt] = __builtin_amdgcn_mfma_f32_16x16x32_bf16(vh, pf, oacc[dt], 0, 0, 0);
                oacc[dt] = __builtin_amdgcn_mfma_f32_16x16x32_bf16(vl, pf, oacc[dt], 0, 0, 0);
            }
        }

        if (i + 1 < nt_cnt) { ASTORE(sm + ((cur ^ 1) * 32768)); cur ^= 1; }
    }
#undef ALOAD
#undef ASTORE

    // ---- store raw partials (no normalize; combine does it)
    const int r = qbase + lq;
    const int pb = (h * 2 + kc) * 64;
    #pragma unroll
    for (int dt = 0; dt < 4; ++dt) {
        #pragma unroll
        for (int j = 0; j < 4; ++j) {
            const int d = dt * 16 + lg * 4 + j;
            Opart[(size_t)(pb + d) * T + r] = oacc[dt][j];
        }
    }
    if (lane < 16) {
        Mpart[(size_t)(h * 2 + kc) * T + r] = m2;
        Lpart[(size_t)(h * 2 + kc) * T + r] = l;
    }
}

// --------------------------------------------- attention: 2-way combine -> bf16 AO[t][o]
__global__ __launch_bounds__(256) void attn_combine_kernel(
    const float* __restrict__ Opart, const float* __restrict__ Mpart,
    const float* __restrict__ Lpart,
    ush* __restrict__ AOH, ush* __restrict__ AOL)
{
    const int idx = blockIdx.x * 256 + threadIdx.x;
    const int h = idx >> 11;
    const int r = idx & (T - 1);

    const float m0 = Mpart[(h * 2 + 0) * T + r], l0 = Lpart[(h * 2 + 0) * T + r];
    const float m1 = Mpart[(h * 2 + 1) * T + r], l1 = Lpart[(h * 2 + 1) * T + r];
    const float M = fmaxf(m0, m1);
    float w0 = exp2f(m0 - M), w1 = exp2f(m1 - M);
    const float L = l0 * w0 + l1 * w1;
    const float invL = 1.0f / L;
    w0 *= invL; w1 *= invL;

    #pragma unroll
    for (int d4 = 0; d4 < 16; ++d4) {
        ushort4 hh, ll;
        #pragma unroll
        for (int j = 0; j < 4; ++j) {
            const int d = d4 * 4 + j;
            const float acc = Opart[((h * 2 + 0) * 64 + d) * (size_t)T + r] * w0
                            + Opart[((h * 2 + 1) * 64 + d) * (size_t)T + r] * w1;
            const ush hv = f2bf(acc);
            ((ush*)&hh)[j] = hv;
            ((ush*)&ll)[j] = f2bf(acc - bf2f(hv));
        }
        *(ushort4*)&AOH[(size_t)r * QDIM + h * 64 + d4 * 4] = hh;
        *(ushort4*)&AOL[(size_t)r * QDIM + h * 64 + d4 * 4] = ll;
    }
}

// --------------------------------------------- O-proj MFMA + bias + residual, true 2-phase
#define PSA_H 0
#define PSA_L 8192
#define PSW_H 16384
#define PSW_L 24576

__global__ __launch_bounds__(256) void oproj_mfma_kernel(
    const ush* __restrict__ AOH, const ush* __restrict__ AOL,
    const ush* __restrict__ OWH, const ush* __restrict__ OWL,
    const float* __restrict__ o_b, const float* __restrict__ x,
    float* __restrict__ out)
{
    const int t0 = blockIdx.x * 64;
    const int c0 = blockIdx.y * 64;
    const int tid = threadIdx.x;
    const int wave = tid >> 6, lane = tid & 63;
    const int lg = lane >> 4, lq = lane & 15;
    const int wr = wave >> 1, wc = wave & 1;

    __shared__ __align__(16) unsigned char sm[65536];

    const int srow0 = tid >> 3, srow1 = srow0 + 32, scc = tid & 7;
    const int dst0 = srow0 * 128 + ((scc * 16) ^ ((srow0 & 7) << 4));
    const int dst1 = srow1 * 128 + ((scc * 16) ^ ((srow1 & 7) << 4));

    uint4 xh0, xl0, wh0, wl0, xh1, xl1, wh1, wl1;

#define PLOAD(k_) do { \
    xh0 = *(const uint4*)&AOH[(size_t)(t0 + srow0) * QDIM + (k_) + scc * 8]; \
    xl0 = *(const uint4*)&AOL[(size_t)(t0 + srow0) * QDIM + (k_) + scc * 8]; \
    wh0 = *(const uint4*)&OWH[(size_t)(c0 + srow0) * QDIM + (k_) + scc * 8]; \
    wl0 = *(const uint4*)&OWL[(size_t)(c0 + srow0) * QDIM + (k_) + scc * 8]; \
    xh1 = *(const uint4*)&AOH[(size_t)(t0 + srow1) * QDIM + (k_) + scc * 8]; \
    xl1 = *(const uint4*)&AOL[(size_t)(t0 + srow1) * QDIM + (k_) + scc * 8]; \
    wh1 = *(const uint4*)&OWH[(size_t)(c0 + srow1) * QDIM + (k_) + scc * 8]; \
    wl1 = *(const uint4*)&OWL[(size_t)(c0 + srow1) * QDIM + (k_) + scc * 8]; \
} while (0)

#define PSTORE(b_) do { \
    *(uint4*)((b_) + PSA_H + dst0) = xh0; \
    *(uint4*)((b_) + PSA_L + dst0) = xl0; \
    *(uint4*)((b_) + PSW_H + dst0) = wh0; \
    *(uint4*)((b_) + PSW_L + dst0) = wl0; \
    *(uint4*)((b_) + PSA_H + dst1) = xh1; \
    *(uint4*)((b_) + PSA_L + dst1) = xl1; \
    *(uint4*)((b_) + PSW_H + dst1) = wh1; \
    *(uint4*)((b_) + PSW_L + dst1) = wl1; \
} while (0)

    float4v acc[2][2];
    acc[0][0] = (float4v)0.f; acc[0][1] = (float4v)0.f;
    acc[1][0] = (float4v)0.f; acc[1][1] = (float4v)0.f;

    PLOAD(0);
    PSTORE(sm);
    int cur = 0;
    for (int s = 0; s < 14; ++s) {
        __syncthreads();
        if (s < 13) PLOAD((s + 1) * 64);
        const unsigned char* smb = sm + cur * 32768;
        #pragma unroll
        for (int kk = 0; kk < 2; ++kk) {
            short8 ah[2], al[2], bh[2], bl[2];
            #pragma unroll
            for (int nt = 0; nt < 2; ++nt) {
                const int row = wc * 32 + nt * 16 + lq;
                const int col = (kk * 64 + lg * 16) ^ ((row & 7) << 4);
                bh[nt] = *(const short8*)(smb + PSA_H + row * 128 + col);
                bl[nt] = *(const short8*)(smb + PSA_L + row * 128 + col);
            }
            #pragma unroll
            for (int mt = 0; mt < 2; ++mt) {
                const int row = wr * 32 + mt * 16 + lq;
                const int col = (kk * 64 + lg * 16) ^ ((row & 7) << 4);
                ah[mt] = *(const short8*)(smb + PSW_H + row * 128 + col);
                al[mt] = *(const short8*)(smb + PSW_L + row * 128 + col);
            }
            #pragma unroll
            for (int mt = 0; mt < 2; ++mt) {
                #pragma unroll
                for (int nt = 0; nt < 2; ++nt) {
                    acc[mt][nt] = __builtin_amdgcn_mfma_f32_16x16x32_bf16(ah[mt], bh[nt], acc[mt][nt], 0, 0, 0);
                    acc[mt][nt] = __builtin_amdgcn_mfma_f32_16x16x32_bf16(ah[mt], bl[nt], acc[mt][nt], 0, 0, 0);
                    acc[mt][nt] = __builtin_amdgcn_mfma_f32_16x16x32_bf16(al[mt], bh[nt], acc[mt][nt], 0, 0, 0);
                }
            }
        }
        if (s < 13) { PSTORE(sm + ((cur ^ 1) * 32768)); cur ^= 1; }
    }
#undef PLOAD
#undef PSTORE

    #pragma unroll
    for (int mt = 0; mt < 2; ++mt) {
        const int cb = c0 + wr * 32 + mt * 16 + lg * 4;
        #pragma unroll
        for (int nt = 0; nt < 2; ++nt) {
            const int t = t0 + wc * 32 + nt * 16 + lq;
            #pragma unroll
            for (int j = 0; j < 4; ++j) {
                const int c = cb + j;
                out[(size_t)c * T + t] = acc[mt][nt][j] + o_b[c] + x[(size_t)c * T + t];
            }
        }
    }
}

// ---------------------------------------------------------------- launcher
extern "C" void kernel_launch(void* const* d_in, const int* in_sizes, int n_in,
                              void* d_out, int out_size, void* d_ws, size_t ws_size,
                              hipStream_t stream) {
    const float* x        = (const float*)d_in[0];
    const float* rope_cos = (const float*)d_in[1];
    const float* rope_sin = (const float*)d_in[2];
    const float* norm_w   = (const float*)d_in[4];
    const float* qkv_w    = (const float*)d_in[5];
    const float* qkv_b    = (const float*)d_in[6];
    const float* o_w      = (const float*)d_in[7];
    const float* o_b      = (const float*)d_in[8];
    const float* sinks    = (const float*)d_in[9];
    float* out = (float*)d_out;

    float* ws    = (float*)d_ws;
    float* rstd  = ws;                       // 2048
    float* Opart = rstd + 2048;              // NH*2*HD*T = 3670016
    float* Mpart = Opart + 3670016;          // NH*2*T = 57344
    float* Lpart = Mpart + 57344;            // 57344
    ush* bws = (ush*)(Lpart + 57344);
    ush* Qh  = bws;                          // 1835008
    ush* Ql  = Qh  + 1835008;
    ush* Kh  = Ql  + 1835008;                // 262144
    ush* Kl  = Kh  + 262144;
    ush* Vth = Kl  + 262144;
    ush* Vtl = Vth + 262144;
    ush* XnH = Vtl + 262144;                 // 1310720
    ush* XnL = XnH + 1310720;
    ush* WqH = XnL + 1310720;                // 737280
    ush* WqL = WqH + 737280;
    ush* OWH = WqL + 737280;                 // 573440
    ush* OWL = OWH + 573440;
    ush* AOH = OWL + 573440;                 // 1835008
    ush* AOL = AOH + 1835008;

    rstd_kernel<<<32, 256, 0, stream>>>(x, rstd);
    cast2_kernel<<<1280, 256, 0, stream>>>(qkv_w, WqH, WqL, QKV_DIM * DM / 4,
                                           o_w, OWH, OWL);
    xnorm_kernel<<<dim3(32, 10), 256, 0, stream>>>(x, norm_w, rstd, XnH, XnL);
    qkv_mfma_kernel<<<dim3(32, 18), 256, 0, stream>>>(
        XnH, XnL, WqH, WqL, qkv_b, rope_cos, rope_sin, Qh, Ql, Kh, Kl, Vth, Vtl);
    attn_mfma_kernel<<<dim3(32, NH, 2), 256, 0, stream>>>(
        Qh, Ql, Kh, Kl, Vth, Vtl, sinks, Opart, Mpart, Lpart);
    attn_combine_kernel<<<NH * T / 256, 256, 0, stream>>>(Opart, Mpart, Lpart, AOH, AOL);
    oproj_mfma_kernel<<<dim3(32, 10), 256, 0, stream>>>(AOH, AOL, OWH, OWL, o_b, x, out);
}

// Round 12
// 246.775 us; speedup vs baseline: 1.0600x; 1.0600x over previous
//
#include <hip/hip_runtime.h>
#include <math.h>

#define T 2048
#define DM 640
#define NH 14
#define NKV 2
#define HPK 7
#define HD 64
#define QDIM 896
#define QKV_DIM 1152

// 64^-0.25 * sqrt(log2(e)): folds base-2 softmax into Q/K scaling
constexpr float QK_SCALE2 = 0.35355339059327373f * 1.2011224087864498f;
constexpr float EPSF = 1e-5f;

typedef __attribute__((ext_vector_type(8))) short short8;   // 8 bf16 = 4 VGPR
typedef __attribute__((ext_vector_type(4))) float float4v;  // MFMA acc
typedef unsigned short ush;

static __device__ __forceinline__ ush f2bf(float f) {
    union { float f; unsigned u; } v; v.f = f;
    unsigned r = v.u + 0x7fffu + ((v.u >> 16) & 1u);
    return (ush)(r >> 16);
}
static __device__ __forceinline__ float bf2f(ush s) {
    union { unsigned u; float f; } v; v.u = ((unsigned)s) << 16;
    return v.f;
}

// ---------------------------------------------------------------- RMSNorm rstd (fused)
__global__ __launch_bounds__(256) void rstd_kernel(
    const float* __restrict__ x, float* __restrict__ rstd)
{
    const int t0 = blockIdx.x * 64;
    const int tl = threadIdx.x & 63, cg = threadIdx.x >> 6;
    __shared__ float red[4][64];
    float ss = 0.f;
    for (int c = cg; c < DM; c += 4) {
        const float v = x[(size_t)c * T + t0 + tl];
        ss = fmaf(v, v, ss);
    }
    red[cg][tl] = ss;
    __syncthreads();
    if (threadIdx.x < 64) {
        const float s = red[0][tl] + red[1][tl] + red[2][tl] + red[3][tl];
        rstd[t0 + tl] = rsqrtf(s * (1.0f / DM) + EPSF);
    }
}

// ------------------------------------------------- both weight casts in one launch
__global__ __launch_bounds__(256) void cast2_kernel(
    const float* __restrict__ a, ush* __restrict__ ah, ush* __restrict__ al, int na4,
    const float* __restrict__ b, ush* __restrict__ bh, ush* __restrict__ bl)
{
    const int i = blockIdx.x * 256 + threadIdx.x;
    const float* src; ush *dh, *dl; int j;
    if (i < na4) { src = a; dh = ah; dl = al; j = i; }
    else         { src = b; dh = bh; dl = bl; j = i - na4; }
    const float4 v = ((const float4*)src)[j];
    ushort4 h, l;
    h.x = f2bf(v.x); l.x = f2bf(v.x - bf2f(h.x));
    h.y = f2bf(v.y); l.y = f2bf(v.y - bf2f(h.y));
    h.z = f2bf(v.z); l.z = f2bf(v.z - bf2f(h.z));
    h.w = f2bf(v.w); l.w = f2bf(v.w - bf2f(h.w));
    ((ushort4*)dh)[j] = h;
    ((ushort4*)dl)[j] = l;
}

// ------------------------------------------------- normed x, transposed to [t][c]
__global__ __launch_bounds__(256) void xnorm_kernel(
    const float* __restrict__ x, const float* __restrict__ norm_w,
    const float* __restrict__ rstd,
    ush* __restrict__ XnH, ush* __restrict__ XnL)
{
    const int tid = threadIdx.x;
    const int t0 = blockIdx.x * 64;
    const int c0 = blockIdx.y * 64;
    __shared__ float xs[64][65];

    #pragma unroll
    for (int it = 0; it < 4; ++it) {
        const int r = (tid >> 4) + it * 16;
        const int cl = (tid & 15) * 4;
        const float4 v = *(const float4*)&x[(size_t)(c0 + r) * T + t0 + cl];
        xs[r][cl + 0] = v.x; xs[r][cl + 1] = v.y;
        xs[r][cl + 2] = v.z; xs[r][cl + 3] = v.w;
    }
    __syncthreads();
    #pragma unroll
    for (int it = 0; it < 4; ++it) {
        const int tr = (tid >> 4) + it * 16;
        const int cl = (tid & 15) * 4;
        const float rs = rstd[t0 + tr];
        ushort4 h, l;
        const float v0 = xs[cl + 0][tr] * norm_w[c0 + cl + 0] * rs;
        const float v1 = xs[cl + 1][tr] * norm_w[c0 + cl + 1] * rs;
        const float v2 = xs[cl + 2][tr] * norm_w[c0 + cl + 2] * rs;
        const float v3 = xs[cl + 3][tr] * norm_w[c0 + cl + 3] * rs;
        h.x = f2bf(v0); l.x = f2bf(v0 - bf2f(h.x));
        h.y = f2bf(v1); l.y = f2bf(v1 - bf2f(h.y));
        h.z = f2bf(v2); l.z = f2bf(v2 - bf2f(h.z));
        h.w = f2bf(v3); l.w = f2bf(v3 - bf2f(h.w));
        *(ushort4*)&XnH[(size_t)(t0 + tr) * DM + c0 + cl] = h;
        *(ushort4*)&XnL[(size_t)(t0 + tr) * DM + c0 + cl] = l;
    }
}

// ------------------------------------------------- QKV MFMA GEMM (+bias+RoPE)
// single 32KB LDS buffer + T14 reg-staging -> 5 blocks/CU
#define QSX_H 0
#define QSX_L 8192
#define QSW_H 16384
#define QSW_L 24576

__global__ __launch_bounds__(256) void qkv_mfma_kernel(
    const ush* __restrict__ XnH, const ush* __restrict__ XnL,
    const ush* __restrict__ WH, const ush* __restrict__ WL,
    const float* __restrict__ qkv_b, const float* __restrict__ rope_cos,
    const float* __restrict__ rope_sin,
    ush* __restrict__ Qh, ush* __restrict__ Ql,
    ush* __restrict__ Kh, ush* __restrict__ Kl,
    ush* __restrict__ Vth, ush* __restrict__ Vtl)
{
    const int t0 = blockIdx.x * 64;
    const int o0 = blockIdx.y * 64;
    const int tid = threadIdx.x;
    const int wave = tid >> 6, lane = tid & 63;
    const int lg = lane >> 4, lq = lane & 15;
    const int wr = wave >> 1, wc = wave & 1;

    __shared__ __align__(16) unsigned char sm[32768];

    const int srow0 = tid >> 3, srow1 = srow0 + 32, scc = tid & 7;
    const int dst0 = srow0 * 128 + ((scc * 16) ^ ((srow0 & 7) << 4));
    const int dst1 = srow1 * 128 + ((scc * 16) ^ ((srow1 & 7) << 4));

    uint4 xh0, xl0, wh0, wl0, xh1, xl1, wh1, wl1;

#define QLOAD(c_) do { \
    xh0 = *(const uint4*)&XnH[(size_t)(t0 + srow0) * DM + (c_) + scc * 8]; \
    xl0 = *(const uint4*)&XnL[(size_t)(t0 + srow0) * DM + (c_) + scc * 8]; \
    wh0 = *(const uint4*)&WH [(size_t)(o0 + srow0) * DM + (c_) + scc * 8]; \
    wl0 = *(const uint4*)&WL [(size_t)(o0 + srow0) * DM + (c_) + scc * 8]; \
    xh1 = *(const uint4*)&XnH[(size_t)(t0 + srow1) * DM + (c_) + scc * 8]; \
    xl1 = *(const uint4*)&XnL[(size_t)(t0 + srow1) * DM + (c_) + scc * 8]; \
    wh1 = *(const uint4*)&WH [(size_t)(o0 + srow1) * DM + (c_) + scc * 8]; \
    wl1 = *(const uint4*)&WL [(size_t)(o0 + srow1) * DM + (c_) + scc * 8]; \
} while (0)

#define QSTORE() do { \
    *(uint4*)(sm + QSX_H + dst0) = xh0; \
    *(uint4*)(sm + QSX_L + dst0) = xl0; \
    *(uint4*)(sm + QSW_H + dst0) = wh0; \
    *(uint4*)(sm + QSW_L + dst0) = wl0; \
    *(uint4*)(sm + QSX_H + dst1) = xh1; \
    *(uint4*)(sm + QSX_L + dst1) = xl1; \
    *(uint4*)(sm + QSW_H + dst1) = wh1; \
    *(uint4*)(sm + QSW_L + dst1) = wl1; \
} while (0)

    float4v acc[2][2];
    acc[0][0] = (float4v)0.f; acc[0][1] = (float4v)0.f;
    acc[1][0] = (float4v)0.f; acc[1][1] = (float4v)0.f;

    QLOAD(0);
    for (int s = 0; s < 10; ++s) {
        QSTORE();                              // waits vmcnt for staged regs
        __syncthreads();                       // staging visible
        if (s < 9) QLOAD((s + 1) * 64);        // issue next loads; overlap compute
        #pragma unroll
        for (int kk = 0; kk < 2; ++kk) {
            short8 ah[2], al[2], bh[2], bl[2];
            #pragma unroll
            for (int nt = 0; nt < 2; ++nt) {
                const int row = wc * 32 + nt * 16 + lq;
                const int col = (kk * 64 + lg * 16) ^ ((row & 7) << 4);
                bh[nt] = *(const short8*)(sm + QSX_H + row * 128 + col);
                bl[nt] = *(const short8*)(sm + QSX_L + row * 128 + col);
            }
            #pragma unroll
            for (int mt = 0; mt < 2; ++mt) {
                const int row = wr * 32 + mt * 16 + lq;
                const int col = (kk * 64 + lg * 16) ^ ((row & 7) << 4);
                ah[mt] = *(const short8*)(sm + QSW_H + row * 128 + col);
                al[mt] = *(const short8*)(sm + QSW_L + row * 128 + col);
            }
            #pragma unroll
            for (int mt = 0; mt < 2; ++mt) {
                #pragma unroll
                for (int nt = 0; nt < 2; ++nt) {
                    acc[mt][nt] = __builtin_amdgcn_mfma_f32_16x16x32_bf16(ah[mt], bh[nt], acc[mt][nt], 0, 0, 0);
                    acc[mt][nt] = __builtin_amdgcn_mfma_f32_16x16x32_bf16(ah[mt], bl[nt], acc[mt][nt], 0, 0, 0);
                    acc[mt][nt] = __builtin_amdgcn_mfma_f32_16x16x32_bf16(al[mt], bh[nt], acc[mt][nt], 0, 0, 0);
                }
            }
        }
        if (s < 9) __syncthreads();            // reads done before next overwrite
    }
#undef QLOAD
#undef QSTORE

    const int by = blockIdx.y;
    #pragma unroll
    for (int mt = 0; mt < 2; ++mt) {
        const int d0 = wr * 32 + mt * 16 + lg * 4;
        #pragma unroll
        for (int nt = 0; nt < 2; ++nt) {
            const int t = t0 + wc * 32 + nt * 16 + lq;
            if (by < 16) { // Q or K: bias + rope + scale (incl sqrt(log2e))
                const float e0 = acc[mt][nt][0] + qkv_b[o0 + d0 + 0];
                const float d1 = acc[mt][nt][1] + qkv_b[o0 + d0 + 1];
                const float e2 = acc[mt][nt][2] + qkv_b[o0 + d0 + 2];
                const float d3 = acc[mt][nt][3] + qkv_b[o0 + d0 + 3];
                const float c0v = rope_cos[t * 32 + (d0 >> 1)];
                const float s0v = rope_sin[t * 32 + (d0 >> 1)];
                const float c1v = rope_cos[t * 32 + (d0 >> 1) + 1];
                const float s1v = rope_sin[t * 32 + (d0 >> 1) + 1];
                const float r0 = (e0 * c0v - d1 * s0v) * QK_SCALE2;
                const float r1 = (d1 * c0v + e0 * s0v) * QK_SCALE2;
                const float r2 = (e2 * c1v - d3 * s1v) * QK_SCALE2;
                const float r3 = (d3 * c1v + e2 * s1v) * QK_SCALE2;
                ushort4 h, l;
                h.x = f2bf(r0); l.x = f2bf(r0 - bf2f(h.x));
                h.y = f2bf(r1); l.y = f2bf(r1 - bf2f(h.y));
                h.z = f2bf(r2); l.z = f2bf(r2 - bf2f(h.z));
                h.w = f2bf(r3); l.w = f2bf(r3 - bf2f(h.w));
                if (by < 14) {
                    *(ushort4*)&Qh[((size_t)(by * T + t)) * HD + d0] = h;
                    *(ushort4*)&Ql[((size_t)(by * T + t)) * HD + d0] = l;
                } else {
                    const int h2 = by - 14;
                    *(ushort4*)&Kh[((size_t)(h2 * T + t)) * HD + d0] = h;
                    *(ushort4*)&Kl[((size_t)(h2 * T + t)) * HD + d0] = l;
                }
            } else { // V: bias only, store d-major
                const int h2 = by - 16;
                #pragma unroll
                for (int j = 0; j < 4; ++j) {
                    const float val = acc[mt][nt][j] + qkv_b[o0 + d0 + j];
                    const ush hh = f2bf(val);
                    Vth[((size_t)(h2 * HD + d0 + j)) * T + t] = hh;
                    Vtl[((size_t)(h2 * HD + d0 + j)) * T + t] = f2bf(val - bf2f(hh));
                }
            }
        }
    }
}

// --------------------------------------------- attention: MFMA flash, strided split-K=2
// single-buffer LDS (K hi/lo + V hi = 24KB) + T14 reg-staging -> 4 blocks/CU
__global__ __launch_bounds__(256) void attn_mfma_kernel(
    const ush* __restrict__ Qh, const ush* __restrict__ Ql,
    const ush* __restrict__ Kh, const ush* __restrict__ Kl,
    const ush* __restrict__ Vth, const ush* __restrict__ Vtl,
    const float* __restrict__ sinks,
    float* __restrict__ Opart, float* __restrict__ Mpart, float* __restrict__ Lpart)
{
    const int qt = 31 - (int)blockIdx.x;   // longest blocks dispatch first
    const int h  = blockIdx.y;
    const int kc = blockIdx.z;
    const int kvh = h / HPK;
    const int tid = threadIdx.x;
    const int wave = tid >> 6, lane = tid & 63;
    const int lg = lane >> 4, lq = lane & 15;
    const int qbase = qt * 64 + wave * 16;
    const int myq = qbase + lq;

    __shared__ __align__(16) unsigned char sm[24576 + 4 * 2304];
    unsigned int* Pl = (unsigned int*)(sm + 24576) + wave * (16 * 36);

    short8 qf[2][2];
    #pragma unroll
    for (int kk = 0; kk < 2; ++kk) {
        const size_t qoff = ((size_t)(h * T + myq)) * HD + kk * 32 + lg * 8;
        qf[kk][0] = *(const short8*)&Qh[qoff];
        qf[kk][1] = *(const short8*)&Ql[qoff];
    }

    float4v oacc[4];
    #pragma unroll
    for (int dt = 0; dt < 4; ++dt) oacc[dt] = (float4v)0.f;

    float m2, l;
    if (kc == 0) { m2 = sinks[h]; l = 1.0f; }  // sink logit in base-2 units
    else         { m2 = -3e38f;   l = 0.0f; }

    const ush* Khp = Kh + (size_t)kvh * T * HD;
    const ush* Klp = Kl + (size_t)kvh * T * HD;
    const ush* Vhp = Vth + (size_t)kvh * HD * T;

    const int srow0 = tid >> 3, srow1 = srow0 + 32, scc = tid & 7;
    const int dst0 = srow0 * 128 + ((scc * 16) ^ ((srow0 & 7) << 4));
    const int dst1 = srow1 * 128 + ((scc * 16) ^ ((srow1 & 7) << 4));

    uint4 rk0h, rk0l, rv0h, rk1h, rk1l, rv1h;

#define ALOAD(kb_) do { \
    rk0h = *(const uint4*)(Khp + (size_t)((kb_) + srow0) * HD + scc * 8); \
    rk0l = *(const uint4*)(Klp + (size_t)((kb_) + srow0) * HD + scc * 8); \
    rv0h = *(const uint4*)(Vhp + (size_t)srow0 * T + (kb_) + scc * 8); \
    rk1h = *(const uint4*)(Khp + (size_t)((kb_) + srow1) * HD + scc * 8); \
    rk1l = *(const uint4*)(Klp + (size_t)((kb_) + srow1) * HD + scc * 8); \
    rv1h = *(const uint4*)(Vhp + (size_t)srow1 * T + (kb_) + scc * 8); \
} while (0)

#define ASTORE() do { \
    *(uint4*)(sm + 0     + dst0) = rk0h; \
    *(uint4*)(sm + 8192  + dst0) = rk0l; \
    *(uint4*)(sm + 16384 + dst0) = rv0h; \
    *(uint4*)(sm + 0     + dst1) = rk1h; \
    *(uint4*)(sm + 8192  + dst1) = rk1l; \
    *(uint4*)(sm + 16384 + dst1) = rv1h; \
} while (0)

    const int nt_cnt = (qt >= kc) ? ((qt - kc) >> 1) + 1 : 0;
    if (nt_cnt > 0) ALOAD(kc * 64);

    for (int i = 0; i < nt_cnt; ++i) {
        const int kb = (kc + 2 * i) * 64;
        ASTORE();                                  // waits vmcnt for staged regs
        __syncthreads();                           // staging visible
        if (i + 1 < nt_cnt) ALOAD(kb + 128);       // issue next; overlaps compute

        // ---- S^T = K . Q^T (3-term hi/lo), scores already in base-2 units
        float4v st[4];
        #pragma unroll
        for (int t = 0; t < 4; ++t) st[t] = (float4v)0.f;
        #pragma unroll
        for (int t = 0; t < 4; ++t) {
            const int row = t * 16 + lq;
            const int rb = row * 128;
            const int sw = (row & 7) << 4;
            #pragma unroll
            for (int kk = 0; kk < 2; ++kk) {
                const int col = (kk * 64 + lg * 16) ^ sw;
                const short8 ah = *(const short8*)(sm + rb + col);
                const short8 al = *(const short8*)(sm + 8192 + rb + col);
                st[t] = __builtin_amdgcn_mfma_f32_16x16x32_bf16(ah, qf[kk][0], st[t], 0, 0, 0);
                st[t] = __builtin_amdgcn_mfma_f32_16x16x32_bf16(ah, qf[kk][1], st[t], 0, 0, 0);
                st[t] = __builtin_amdgcn_mfma_f32_16x16x32_bf16(al, qf[kk][0], st[t], 0, 0, 0);
            }
        }

        // ---- causal mask + online softmax (base-2)
        float pmax = -3e38f;
        #pragma unroll
        for (int t = 0; t < 4; ++t) {
            #pragma unroll
            for (int j = 0; j < 4; ++j) {
                const int key = kb + 16 * t + 4 * lg + j;
                const float s = (key > myq) ? -3e38f : st[t][j];
                st[t][j] = s;
                pmax = fmaxf(pmax, s);
            }
        }
        pmax = fmaxf(pmax, __shfl_xor(pmax, 16));
        pmax = fmaxf(pmax, __shfl_xor(pmax, 32));
        if (__any(pmax > m2)) {
            const float mnew = fmaxf(m2, pmax);
            const float corr = exp2f(m2 - mnew);
            l *= corr;
            #pragma unroll
            for (int dt = 0; dt < 4; ++dt) oacc[dt] *= corr;
            m2 = mnew;
        }
        float psum = 0.f;
        #pragma unroll
        for (int t = 0; t < 4; ++t) {
            #pragma unroll
            for (int j = 0; j < 4; ++j) {
                const float p = exp2f(st[t][j] - m2);
                st[t][j] = p;
                psum += p;
            }
        }
        psum += __shfl_xor(psum, 16);
        psum += __shfl_xor(psum, 32);
        l += psum;

        // ---- P^T fragments via per-wave LDS (in-order DS, no barrier needed)
        #pragma unroll
        for (int t = 0; t < 4; ++t) {
            #pragma unroll
            for (int j2 = 0; j2 < 2; ++j2) {
                const unsigned int u = (unsigned int)f2bf(st[t][2 * j2]) |
                                       ((unsigned int)f2bf(st[t][2 * j2 + 1]) << 16);
                Pl[lq * 36 + t * 8 + lg * 2 + j2] = u;
            }
        }

        // ---- O^T += V_hi . P^T
        #pragma unroll
        for (int c = 0; c < 2; ++c) {
            const short8 pf = *(const short8*)&Pl[lq * 36 + c * 16 + lg * 4];
            #pragma unroll
            for (int dt = 0; dt < 4; ++dt) {
                const int row = dt * 16 + lq;
                const int rb = row * 128;
                const int col = (c * 64 + lg * 16) ^ ((row & 7) << 4);
                const short8 vh = *(const short8*)(sm + 16384 + rb + col);
                oacc[dt] = __builtin_amdgcn_mfma_f32_16x16x32_bf16(vh, pf, oacc[dt], 0, 0, 0);
            }
        }

        if (i + 1 < nt_cnt) __syncthreads();       // reads done before next overwrite
    }
#undef ALOAD
#undef ASTORE

    // ---- store raw partials (no normalize; combine does it)
    const int r = qbase + lq;
    const int pb = (h * 2 + kc) * 64;
    #pragma unroll
    for (int dt = 0; dt < 4; ++dt) {
        #pragma unroll
        for (int j = 0; j < 4; ++j) {
            const int d = dt * 16 + lg * 4 + j;
            Opart[(size_t)(pb + d) * T + r] = oacc[dt][j];
        }
    }
    if (lane < 16) {
        Mpart[(size_t)(h * 2 + kc) * T + r] = m2;
        Lpart[(size_t)(h * 2 + kc) * T + r] = l;
    }
}

// --------------------------------------------- attention: 2-way combine -> bf16 AO[t][o]
__global__ __launch_bounds__(256) void attn_combine_kernel(
    const float* __restrict__ Opart, const float* __restrict__ Mpart,
    const float* __restrict__ Lpart,
    ush* __restrict__ AOH, ush* __restrict__ AOL)
{
    const int idx = blockIdx.x * 256 + threadIdx.x;
    const int h = idx >> 11;
    const int r = idx & (T - 1);

    const float m0 = Mpart[(h * 2 + 0) * T + r], l0 = Lpart[(h * 2 + 0) * T + r];
    const float m1 = Mpart[(h * 2 + 1) * T + r], l1 = Lpart[(h * 2 + 1) * T + r];
    const float M = fmaxf(m0, m1);
    float w0 = exp2f(m0 - M), w1 = exp2f(m1 - M);
    const float L = l0 * w0 + l1 * w1;
    const float invL = 1.0f / L;
    w0 *= invL; w1 *= invL;

    #pragma unroll
    for (int d4 = 0; d4 < 16; ++d4) {
        ushort4 hh, ll;
        #pragma unroll
        for (int j = 0; j < 4; ++j) {
            const int d = d4 * 4 + j;
            const float acc = Opart[((h * 2 + 0) * 64 + d) * (size_t)T + r] * w0
                            + Opart[((h * 2 + 1) * 64 + d) * (size_t)T + r] * w1;
            const ush hv = f2bf(acc);
            ((ush*)&hh)[j] = hv;
            ((ush*)&ll)[j] = f2bf(acc - bf2f(hv));
        }
        *(ushort4*)&AOH[(size_t)r * QDIM + h * 64 + d4 * 4] = hh;
        *(ushort4*)&AOL[(size_t)r * QDIM + h * 64 + d4 * 4] = ll;
    }
}

// --------------------------------------------- O-proj MFMA + bias + residual
// single 32KB LDS buffer + T14 reg-staging
#define PSA_H 0
#define PSA_L 8192
#define PSW_H 16384
#define PSW_L 24576

__global__ __launch_bounds__(256) void oproj_mfma_kernel(
    const ush* __restrict__ AOH, const ush* __restrict__ AOL,
    const ush* __restrict__ OWH, const ush* __restrict__ OWL,
    const float* __restrict__ o_b, const float* __restrict__ x,
    float* __restrict__ out)
{
    const int t0 = blockIdx.x * 64;
    const int c0 = blockIdx.y * 64;
    const int tid = threadIdx.x;
    const int wave = tid >> 6, lane = tid & 63;
    const int lg = lane >> 4, lq = lane & 15;
    const int wr = wave >> 1, wc = wave & 1;

    __shared__ __align__(16) unsigned char sm[32768];

    const int srow0 = tid >> 3, srow1 = srow0 + 32, scc = tid & 7;
    const int dst0 = srow0 * 128 + ((scc * 16) ^ ((srow0 & 7) << 4));
    const int dst1 = srow1 * 128 + ((scc * 16) ^ ((srow1 & 7) << 4));

    uint4 xh0, xl0, wh0, wl0, xh1, xl1, wh1, wl1;

#define PLOAD(k_) do { \
    xh0 = *(const uint4*)&AOH[(size_t)(t0 + srow0) * QDIM + (k_) + scc * 8]; \
    xl0 = *(const uint4*)&AOL[(size_t)(t0 + srow0) * QDIM + (k_) + scc * 8]; \
    wh0 = *(const uint4*)&OWH[(size_t)(c0 + srow0) * QDIM + (k_) + scc * 8]; \
    wl0 = *(const uint4*)&OWL[(size_t)(c0 + srow0) * QDIM + (k_) + scc * 8]; \
    xh1 = *(const uint4*)&AOH[(size_t)(t0 + srow1) * QDIM + (k_) + scc * 8]; \
    xl1 = *(const uint4*)&AOL[(size_t)(t0 + srow1) * QDIM + (k_) + scc * 8]; \
    wh1 = *(const uint4*)&OWH[(size_t)(c0 + srow1) * QDIM + (k_) + scc * 8]; \
    wl1 = *(const uint4*)&OWL[(size_t)(c0 + srow1) * QDIM + (k_) + scc * 8]; \
} while (0)

#define PSTORE() do { \
    *(uint4*)(sm + PSA_H + dst0) = xh0; \
    *(uint4*)(sm + PSA_L + dst0) = xl0; \
    *(uint4*)(sm + PSW_H + dst0) = wh0; \
    *(uint4*)(sm + PSW_L + dst0) = wl0; \
    *(uint4*)(sm + PSA_H + dst1) = xh1; \
    *(uint4*)(sm + PSA_L + dst1) = xl1; \
    *(uint4*)(sm + PSW_H + dst1) = wh1; \
    *(uint4*)(sm + PSW_L + dst1) = wl1; \
} while (0)

    float4v acc[2][2];
    acc[0][0] = (float4v)0.f; acc[0][1] = (float4v)0.f;
    acc[1][0] = (float4v)0.f; acc[1][1] = (float4v)0.f;

    PLOAD(0);
    for (int s = 0; s < 14; ++s) {
        PSTORE();
        __syncthreads();
        if (s < 13) PLOAD((s + 1) * 64);
        #pragma unroll
        for (int kk = 0; kk < 2; ++kk) {
            short8 ah[2], al[2], bh[2], bl[2];
            #pragma unroll
            for (int nt = 0; nt < 2; ++nt) {
                const int row = wc * 32 + nt * 16 + lq;
                const int col = (kk * 64 + lg * 16) ^ ((row & 7) << 4);
                bh[nt] = *(const short8*)(sm + PSA_H + row * 128 + col);
                bl[nt] = *(const short8*)(sm + PSA_L + row * 128 + col);
            }
            #pragma unroll
            for (int mt = 0; mt < 2; ++mt) {
                const int row = wr * 32 + mt * 16 + lq;
                const int col = (kk * 64 + lg * 16) ^ ((row & 7) << 4);
                ah[mt] = *(const short8*)(sm + PSW_H + row * 128 + col);
                al[mt] = *(const short8*)(sm + PSW_L + row * 128 + col);
            }
            #pragma unroll
            for (int mt = 0; mt < 2; ++mt) {
                #pragma unroll
                for (int nt = 0; nt < 2; ++nt) {
                    acc[mt][nt] = __builtin_amdgcn_mfma_f32_16x16x32_bf16(ah[mt], bh[nt], acc[mt][nt], 0, 0, 0);
                    acc[mt][nt] = __builtin_amdgcn_mfma_f32_16x16x32_bf16(ah[mt], bl[nt], acc[mt][nt], 0, 0, 0);
                    acc[mt][nt] = __builtin_amdgcn_mfma_f32_16x16x32_bf16(al[mt], bh[nt], acc[mt][nt], 0, 0, 0);
                }
            }
        }
        if (s < 13) __syncthreads();
    }
#undef PLOAD
#undef PSTORE

    #pragma unroll
    for (int mt = 0; mt < 2; ++mt) {
        const int cb = c0 + wr * 32 + mt * 16 + lg * 4;
        #pragma unroll
        for (int nt = 0; nt < 2; ++nt) {
            const int t = t0 + wc * 32 + nt * 16 + lq;
            #pragma unroll
            for (int j = 0; j < 4; ++j) {
                const int c = cb + j;
                out[(size_t)c * T + t] = acc[mt][nt][j] + o_b[c] + x[(size_t)c * T + t];
            }
        }
    }
}

// ---------------------------------------------------------------- launcher
extern "C" void kernel_launch(void* const* d_in, const int* in_sizes, int n_in,
                              void* d_out, int out_size, void* d_ws, size_t ws_size,
                              hipStream_t stream) {
    const float* x        = (const float*)d_in[0];
    const float* rope_cos = (const float*)d_in[1];
    const float* rope_sin = (const float*)d_in[2];
    const float* norm_w   = (const float*)d_in[4];
    const float* qkv_w    = (const float*)d_in[5];
    const float* qkv_b    = (const float*)d_in[6];
    const float* o_w      = (const float*)d_in[7];
    const float* o_b      = (const float*)d_in[8];
    const float* sinks    = (const float*)d_in[9];
    float* out = (float*)d_out;

    float* ws    = (float*)d_ws;
    float* rstd  = ws;                       // 2048
    float* Opart = rstd + 2048;              // NH*2*HD*T = 3670016
    float* Mpart = Opart + 3670016;          // NH*2*T = 57344
    float* Lpart = Mpart + 57344;            // 57344
    ush* bws = (ush*)(Lpart + 57344);
    ush* Qh  = bws;                          // 1835008
    ush* Ql  = Qh  + 1835008;
    ush* Kh  = Ql  + 1835008;                // 262144
    ush* Kl  = Kh  + 262144;
    ush* Vth = Kl  + 262144;
    ush* Vtl = Vth + 262144;
    ush* XnH = Vtl + 262144;                 // 1310720
    ush* XnL = XnH + 1310720;
    ush* WqH = XnL + 1310720;                // 737280
    ush* WqL = WqH + 737280;
    ush* OWH = WqL + 737280;                 // 573440
    ush* OWL = OWH + 573440;
    ush* AOH = OWL + 573440;                 // 1835008
    ush* AOL = AOH + 1835008;

    rstd_kernel<<<32, 256, 0, stream>>>(x, rstd);
    cast2_kernel<<<1280, 256, 0, stream>>>(qkv_w, WqH, WqL, QKV_DIM * DM / 4,
                                           o_w, OWH, OWL);
    xnorm_kernel<<<dim3(32, 10), 256, 0, stream>>>(x, norm_w, rstd, XnH, XnL);
    qkv_mfma_kernel<<<dim3(32, 18), 256, 0, stream>>>(
        XnH, XnL, WqH, WqL, qkv_b, rope_cos, rope_sin, Qh, Ql, Kh, Kl, Vth, Vtl);
    attn_mfma_kernel<<<dim3(32, NH, 2), 256, 0, stream>>>(
        Qh, Ql, Kh, Kl, Vth, Vtl, sinks, Opart, Mpart, Lpart);
    attn_combine_kernel<<<NH * T / 256, 256, 0, stream>>>(Opart, Mpart, Lpart, AOH, AOL);
    oproj_mfma_kernel<<<dim3(32, 10), 256, 0, stream>>>(AOH, AOL, OWH, OWL, o_b, x, out);
}